// Round 8
// baseline (595.331 us; speedup 1.0000x reference)
//
#include <hip/hip_runtime.h>

// Problem constants (B,C,H,W)=(32,64,64,64), code_size=512
#define HWDIM 4096
#define CDIM  64
#define KDIM  512
#define ST_ELEMS   8388608   // 32*64*64*64
#define LOSS_OFF   8519680   // ST_ELEMS + 32*64*64

#define REP64(M) M(0) M(1) M(2) M(3) M(4) M(5) M(6) M(7) M(8) M(9) \
  M(10) M(11) M(12) M(13) M(14) M(15) M(16) M(17) M(18) M(19) \
  M(20) M(21) M(22) M(23) M(24) M(25) M(26) M(27) M(28) M(29) \
  M(30) M(31) M(32) M(33) M(34) M(35) M(36) M(37) M(38) M(39) \
  M(40) M(41) M(42) M(43) M(44) M(45) M(46) M(47) M(48) M(49) \
  M(50) M(51) M(52) M(53) M(54) M(55) M(56) M(57) M(58) M(59) \
  M(60) M(61) M(62) M(63)

// 16-float row chunks via constant AS (R6 — best variant so far).
typedef float vf16 __attribute__((ext_vector_type(16)));
typedef __attribute__((address_space(4))) const vf16 cvf16;

// numpy fp32 pairwise sum-of-squares (AVX-512 npyv emulation) — bit-validated.
__device__ __forceinline__ float np_sumsq64(const float a[64]) {
#pragma clang fp contract(off)
  float v[16];
#pragma unroll
  for (int i = 0; i < 16; ++i) {
    float s0 = a[i]      * a[i];
    float s1 = a[i + 16] * a[i + 16];
    float s2 = a[i + 32] * a[i + 32];
    float s3 = a[i + 48] * a[i + 48];
    v[i] = (s0 + s1) + (s2 + s3);
  }
  float t0 = (v[0] + v[8])  + (v[4] + v[12]);
  float t1 = (v[1] + v[9])  + (v[5] + v[13]);
  float t2 = (v[2] + v[10]) + (v[6] + v[14]);
  float t3 = (v[3] + v[11]) + (v[7] + v[15]);
  return (t0 + t2) + (t1 + t3);
}

// K-split x2: 1024 blocks x 256 threads; block = 128 pixels x 2 code-halves.
// TLP was the pinned variable across R1-R7 (2048 waves -> 2/SIMD, Occ 20%,
// VALUBusy 65%): ~1300 stall cyc/group of just-in-time chunk loads that 2
// waves can't hide. Doubling waves (4/SIMD) hides latency; VGPR ~88 fits the
// 128-reg budget at waves_per_eu(4,4).
__global__ __launch_bounds__(256)
__attribute__((amdgpu_waves_per_eu(4, 4)))
void vq_kernel(
    const float* __restrict__ x, const float* __restrict__ cb,
    float* __restrict__ st, float* __restrict__ idxo, float* __restrict__ loss)
{
  __shared__ float sc[KDIM];
  __shared__ float md[256];
  __shared__ int   mi[256];
  __shared__ float lred[2];

  const int tid  = threadIdx.x;
  const int half = tid >> 7;                  // 0: codes 0..255, 1: 256..511
  const int lane = tid & 127;
  const int b    = blockIdx.x & 31;           // batch index
  const int p    = ((blockIdx.x >> 5) << 7) + lane;  // pixel index 0..4095

  cvf16* rows = (cvf16*)(uintptr_t)cb;        // row k = chunks [4k..4k+3]

  // Per-block codebook sum-of-squares (identical fp32 bits in every block).
  for (int k = tid; k < KDIM; k += 256) {
    float row[64];
#pragma unroll
    for (int c = 0; c < 64; ++c) row[c] = cb[(k << 6) + c];
    sc[k] = np_sumsq64(row);
  }

  // Load this thread's pixel into 64 named, pinned registers (both halves of
  // a pixel load identical values -> identical S bits).
  const float* xp = x + (size_t)b * (CDIM * HWDIM) + p;
#define XLOAD(i) float x##i = xp[(i) * HWDIM]; asm("" : "+v"(x##i));
  REP64(XLOAD)
#undef XLOAD

  // numpy pairwise sum-of-squares of x (same tree, named-register form).
  float S;
  {
#pragma clang fp contract(off)
#define SQ(i, j, k2, l) float v##i = ((x##i * x##i) + (x##j * x##j)) + ((x##k2 * x##k2) + (x##l * x##l));
    SQ(0,16,32,48) SQ(1,17,33,49) SQ(2,18,34,50) SQ(3,19,35,51)
    SQ(4,20,36,52) SQ(5,21,37,53) SQ(6,22,38,54) SQ(7,23,39,55)
    SQ(8,24,40,56) SQ(9,25,41,57) SQ(10,26,42,58) SQ(11,27,43,59)
    SQ(12,28,44,60) SQ(13,29,45,61) SQ(14,30,46,62) SQ(15,31,47,63)
#undef SQ
    float t0 = (v0 + v8)  + (v4 + v12);
    float t1 = (v1 + v9)  + (v5 + v13);
    float t2 = (v2 + v10) + (v6 + v14);
    float t3 = (v3 + v11) + (v7 + v15);
    S = (t0 + t2) + (t1 + t3);
  }
  __syncthreads();

  // Argmin over this half's 256 codes, 4 rows/group. Per-k dist bits
  // identical to R1-R7: sequential fused-FMA ascending c; (S-2d)+sc[k];
  // ascending-k strict '<'.
  const int kstart = half << 8;
  float bestd = __builtin_inff();
  int   besti = kstart;

#define FF(T, XI) \
    d0 = __builtin_fmaf(x##XI, c0[T], d0); \
    d1 = __builtin_fmaf(x##XI, c1[T], d1); \
    d2 = __builtin_fmaf(x##XI, c2[T], d2); \
    d3 = __builtin_fmaf(x##XI, c3[T], d3);
#define CHUNK(J, A0,A1,A2,A3,A4,A5,A6,A7,A8,A9,A10,A11,A12,A13,A14,A15) \
  { vf16 c0 = rows[rb + (J)];      vf16 c1 = rows[rb + 4 + (J)];        \
    vf16 c2 = rows[rb + 8 + (J)];  vf16 c3 = rows[rb + 12 + (J)];       \
    FF(0,A0) FF(1,A1) FF(2,A2) FF(3,A3) FF(4,A4) FF(5,A5) FF(6,A6)      \
    FF(7,A7) FF(8,A8) FF(9,A9) FF(10,A10) FF(11,A11) FF(12,A12)         \
    FF(13,A13) FF(14,A14) FF(15,A15) }

  for (int k = kstart; k < kstart + 256; k += 4) {
    const int rb = k << 2;
    float d0 = 0.f, d1 = 0.f, d2 = 0.f, d3 = 0.f;
    CHUNK(0,  0, 1, 2, 3, 4, 5, 6, 7, 8, 9,10,11,12,13,14,15)
    CHUNK(1, 16,17,18,19,20,21,22,23,24,25,26,27,28,29,30,31)
    CHUNK(2, 32,33,34,35,36,37,38,39,40,41,42,43,44,45,46,47)
    CHUNK(3, 48,49,50,51,52,53,54,55,56,57,58,59,60,61,62,63)
    float e0, e1, e2, e3;
    {
#pragma clang fp contract(off)
      e0 = (S - (d0 + d0)) + sc[k];
      e1 = (S - (d1 + d1)) + sc[k + 1];
      e2 = (S - (d2 + d2)) + sc[k + 2];
      e3 = (S - (d3 + d3)) + sc[k + 3];
    }
    if (e0 < bestd) { bestd = e0; besti = k; }
    if (e1 < bestd) { bestd = e1; besti = k + 1; }
    if (e2 < bestd) { bestd = e2; besti = k + 2; }
    if (e3 < bestd) { bestd = e3; besti = k + 3; }
  }
#undef CHUNK
#undef FF

  // Merge halves: half0 wins non-strict ties (lower indices) — np.argmin
  // first-min semantics preserved exactly.
  md[tid] = bestd;
  mi[tid] = besti;
  __syncthreads();

  float lsum = 0.f;
  if (half == 0) {
    float od = md[tid + 128];
    if (od < bestd) { bestd = od; besti = mi[tid + 128]; }

    // Epilogue (half0 threads only): gather chosen row, write st (coalesced:
    // lane = consecutive p), loss partial, index.
    const float* crow = cb + (besti << 6);
    float* stp = st + (size_t)b * (CDIM * HWDIM) + p;
#define EPI(i) { float cv = crow[i]; float df; \
    { _Pragma("clang fp contract(off)") df = cv - x##i; } \
    lsum = __builtin_fmaf(df, df, lsum); stp[(i) * HWDIM] = cv; }
    REP64(EPI)
#undef EPI
    idxo[b * HWDIM + p] = (float)besti;
  }

  // Block reduce loss (upper half contributes 0), one atomic per block.
#pragma unroll
  for (int off = 32; off > 0; off >>= 1) lsum += __shfl_down(lsum, off);
  if ((tid & 63) == 0 && half == 0) lred[tid >> 6] = lsum;
  __syncthreads();
  if (tid == 0) {
    float t = lred[0] + lred[1];
    atomicAdd(loss, t * (1.25f / 8388608.f));
  }
}

extern "C" void kernel_launch(void* const* d_in, const int* in_sizes, int n_in,
                              void* d_out, int out_size, void* d_ws, size_t ws_size,
                              hipStream_t stream) {
  const float* x  = (const float*)d_in[0];   // (32,64,64,64) fp32
  const float* cb = (const float*)d_in[1];   // (512,64) fp32
  float* st   = (float*)d_out;               // (32,64,64,64)
  float* idxo = (float*)d_out + ST_ELEMS;    // (32,64,64) as float
  float* loss = (float*)d_out + LOSS_OFF;    // scalar

  hipMemsetAsync(loss, 0, sizeof(float), stream);  // d_out is poisoned each call
  vq_kernel<<<dim3(1024), dim3(256), 0, stream>>>(x, cb, st, idxo, loss);
}

// Round 9
// 329.526 us; speedup vs baseline: 1.8066x; 1.8066x over previous
//
#include <hip/hip_runtime.h>

// Problem constants (B,C,H,W)=(32,64,64,64), code_size=512
#define HWDIM 4096
#define CDIM  64
#define KDIM  512
#define ST_ELEMS   8388608   // 32*64*64*64
#define LOSS_OFF   8519680   // ST_ELEMS + 32*64*64

#define REP64(M) M(0) M(1) M(2) M(3) M(4) M(5) M(6) M(7) M(8) M(9) \
  M(10) M(11) M(12) M(13) M(14) M(15) M(16) M(17) M(18) M(19) \
  M(20) M(21) M(22) M(23) M(24) M(25) M(26) M(27) M(28) M(29) \
  M(30) M(31) M(32) M(33) M(34) M(35) M(36) M(37) M(38) M(39) \
  M(40) M(41) M(42) M(43) M(44) M(45) M(46) M(47) M(48) M(49) \
  M(50) M(51) M(52) M(53) M(54) M(55) M(56) M(57) M(58) M(59) \
  M(60) M(61) M(62) M(63)

// 16-float tuple held in SGPRs (SGPR_512 class) via inline-asm "s" constraint.
typedef float vf16 __attribute__((ext_vector_type(16)));

// numpy fp32 pairwise sum-of-squares (AVX-512 npyv emulation) — bit-validated.
__device__ __forceinline__ float np_sumsq64(const float a[64]) {
#pragma clang fp contract(off)
  float v[16];
#pragma unroll
  for (int i = 0; i < 16; ++i) {
    float s0 = a[i]      * a[i];
    float s1 = a[i + 16] * a[i + 16];
    float s2 = a[i + 32] * a[i + 32];
    float s3 = a[i + 48] * a[i + 48];
    v[i] = (s0 + s1) + (s2 + s3);
  }
  float t0 = (v[0] + v[8])  + (v[4] + v[12]);
  float t1 = (v[1] + v[9])  + (v[5] + v[13]);
  float t2 = (v[2] + v[10]) + (v[6] + v[14]);
  float t3 = (v[3] + v[11]) + (v[7] + v[15]);
  return (t0 + t2) + (t1 + t3);
}

// Issue two s_load_dwordx16 (one 32-float half-row) into SGPR tuples.
// Scalar pipe: zero VGPR-file delivery cost (R1-R8: per-lane vector delivery
// of broadcast rows costs ~8cyc/16B-load ~= the FMA cost — the 192us wall).
#define LOADH(R0, R1, CBP, O0, O1) \
  asm volatile("s_load_dwordx16 %0, %2, %3\n\t" \
               "s_load_dwordx16 %1, %2, %4" \
               : "=s"(R0), "=s"(R1) \
               : "s"(CBP), "s"(O0), "s"(O1))

// Drain SMEM. Ties the buffers as "+s" so no use of R0/R1 can be scheduled
// before the wait (compiler doesn't model asm-internal SMEM otherwise).
#define WAITLK(R0, R1) \
  asm volatile("s_waitcnt lgkmcnt(0)" : "+s"(R0), "+s"(R1))

// 16 sequential FMAs of one chunk into the single chain accumulator c.
#define CH(R, T, XI) c = __builtin_fmaf(x##XI, R[T], c);
#define G16(R, A0,A1,A2,A3,A4,A5,A6,A7,A8,A9,A10,A11,A12,A13,A14,A15) \
  CH(R,0,A0) CH(R,1,A1) CH(R,2,A2) CH(R,3,A3) CH(R,4,A4) CH(R,5,A5) \
  CH(R,6,A6) CH(R,7,A7) CH(R,8,A8) CH(R,9,A9) CH(R,10,A10) CH(R,11,A11) \
  CH(R,12,A12) CH(R,13,A13) CH(R,14,A14) CH(R,15,A15)

// R6 frame: 512 blocks x 256 thr, waves_per_eu(2,2) — VGPR 88, no spill
// (R8's (4,4) spilled x to HBM: VGPR 64, FETCH+12MB, 2.2x regression).
__global__ __launch_bounds__(256)
__attribute__((amdgpu_waves_per_eu(2, 2)))
void vq_kernel(
    const float* __restrict__ x, const float* __restrict__ cb,
    float* __restrict__ st, float* __restrict__ idxo, float* __restrict__ loss)
{
  __shared__ float sc[KDIM];
  __shared__ float lred[4];

  const int tid = threadIdx.x;
  const int b   = blockIdx.x & 31;                 // batch index
  const int p   = ((blockIdx.x >> 5) << 8) + tid;  // pixel index 0..4095

  // Per-block codebook sum-of-squares (identical fp32 bits in every block).
  for (int k = tid; k < KDIM; k += 256) {
    float row[64];
#pragma unroll
    for (int c = 0; c < 64; ++c) row[c] = cb[(k << 6) + c];
    sc[k] = np_sumsq64(row);
  }

  // Load this thread's pixel into 64 named, pinned registers.
  const float* xp = x + (size_t)b * (CDIM * HWDIM) + p;
#define XLOAD(i) float x##i = xp[(i) * HWDIM]; asm("" : "+v"(x##i));
  REP64(XLOAD)
#undef XLOAD

  // numpy pairwise sum-of-squares of x (same tree, named-register form).
  float S;
  {
#pragma clang fp contract(off)
#define SQ(i, j, k2, l) float v##i = ((x##i * x##i) + (x##j * x##j)) + ((x##k2 * x##k2) + (x##l * x##l));
    SQ(0,16,32,48) SQ(1,17,33,49) SQ(2,18,34,50) SQ(3,19,35,51)
    SQ(4,20,36,52) SQ(5,21,37,53) SQ(6,22,38,54) SQ(7,23,39,55)
    SQ(8,24,40,56) SQ(9,25,41,57) SQ(10,26,42,58) SQ(11,27,43,59)
    SQ(12,28,44,60) SQ(13,29,45,61) SQ(14,30,46,62) SQ(15,31,47,63)
#undef SQ
    float t0 = (v0 + v8)  + (v4 + v12);
    float t1 = (v1 + v9)  + (v5 + v13);
    float t2 = (v2 + v10) + (v6 + v14);
    float t3 = (v3 + v11) + (v7 + v15);
    S = (t0 + t2) + (t1 + t3);
  }
  __syncthreads();

  // Argmin over 512 codes. Row data streamed through SGPRs (s_load_dwordx16),
  // half-row double-buffered: issue next half's loads before FMA-ing the
  // current half so ~64cyc of SMEM latency hides under the chain; the rest
  // hides under the partner wave. dist numerics BIT-IDENTICAL to R1-R6:
  // single sequential fused-FMA chain ascending c (1 fma/4cyc/wave x 2 waves
  // = full SIMD issue rate); (S - 2*dot) + sc[k]; ascending-k strict '<'.
  float bestd = __builtin_inff();
  int   besti = 0;
  vf16 a0, a1, b0, b1;

  LOADH(a0, a1, cb, 0u, 64u);          // row 0, dims 0..31
  WAITLK(a0, a1);

  for (int k = 0; k < KDIM; ++k) {
    const unsigned base = (unsigned)k << 8;        // byte offset of row k
    LOADH(b0, b1, cb, base + 128u, base + 192u);   // row k, dims 32..63
    float c = 0.f;
    G16(a0,  0, 1, 2, 3, 4, 5, 6, 7, 8, 9,10,11,12,13,14,15)
    G16(a1, 16,17,18,19,20,21,22,23,24,25,26,27,28,29,30,31)
    WAITLK(b0, b1);
    unsigned nb = base + 256u;                     // row k+1, dims 0..31
    if (nb > 130816u) nb = 130816u;                // k=511: harmless reload
    LOADH(a0, a1, cb, nb, nb + 64u);
    G16(b0, 32,33,34,35,36,37,38,39,40,41,42,43,44,45,46,47)
    G16(b1, 48,49,50,51,52,53,54,55,56,57,58,59,60,61,62,63)
    WAITLK(a0, a1);
    float e;
    {
#pragma clang fp contract(off)
      e = (S - (c + c)) + sc[k];
    }
    if (e < bestd) { bestd = e; besti = k; }
  }

  // Epilogue: gather chosen row (per-lane divergent), write st (coalesced:
  // lane = consecutive p), loss partial, index. Unchanged from R6.
  const float* crow = cb + (besti << 6);
  float* stp = st + (size_t)b * (CDIM * HWDIM) + p;
  float lsum = 0.f;
#define EPI(i) { float cv = crow[i]; float df; \
    { _Pragma("clang fp contract(off)") df = cv - x##i; } \
    lsum = __builtin_fmaf(df, df, lsum); stp[(i) * HWDIM] = cv; }
  REP64(EPI)
#undef EPI

  idxo[b * HWDIM + p] = (float)besti;

  // Block reduce loss, one atomic per block. 1.25/(N*C) is exact pow2*5.
#pragma unroll
  for (int off = 32; off > 0; off >>= 1) lsum += __shfl_down(lsum, off);
  if ((tid & 63) == 0) lred[tid >> 6] = lsum;
  __syncthreads();
  if (tid == 0) {
    float t = (lred[0] + lred[1]) + (lred[2] + lred[3]);
    atomicAdd(loss, t * (1.25f / 8388608.f));
  }
}

extern "C" void kernel_launch(void* const* d_in, const int* in_sizes, int n_in,
                              void* d_out, int out_size, void* d_ws, size_t ws_size,
                              hipStream_t stream) {
  const float* x  = (const float*)d_in[0];   // (32,64,64,64) fp32
  const float* cb = (const float*)d_in[1];   // (512,64) fp32
  float* st   = (float*)d_out;               // (32,64,64,64)
  float* idxo = (float*)d_out + ST_ELEMS;    // (32,64,64) as float
  float* loss = (float*)d_out + LOSS_OFF;    // scalar

  hipMemsetAsync(loss, 0, sizeof(float), stream);  // d_out is poisoned each call
  vq_kernel<<<dim3(512), dim3(256), 0, stream>>>(x, cb, st, idxo, loss);
}